// Round 3
// baseline (209.149 us; speedup 1.0000x reference)
//
#include <hip/hip_runtime.h>

// ---------- types ----------
typedef __bf16 bf16x8 __attribute__((ext_vector_type(8)));
typedef float f32x4 __attribute__((ext_vector_type(4)));
typedef unsigned short u16x8 __attribute__((ext_vector_type(8)));

__device__ inline unsigned short f2bf(float f) {
  union { float f; unsigned u; } a; a.f = f;
  return (unsigned short)((a.u + 0x7fffu + ((a.u >> 16) & 1u)) >> 16); // RNE
}
__device__ inline float bf2f(unsigned short h) {
  union { unsigned u; float f; } a; a.u = ((unsigned)h) << 16;
  return a.f;
}

// ---------- fp32 -> bf16 conversion (query,key,value,Wq,Wk,Wv) ----------
struct CvtArgs {
  const float* src[6];
  unsigned short* dst[6];
};

__global__ __launch_bounds__(256) void cvt6(CvtArgs a) {
  long long i = (long long)blockIdx.x * 256 + threadIdx.x; // one float4 each
  int idx; long long off;
  if (i < 6291456LL) { idx = (int)(i >> 21); off = i & ((1LL << 21) - 1); }
  else { long long j = i - 6291456LL; idx = 3 + (int)(j >> 18); off = j & ((1LL << 18) - 1); }
  float4 v = ((const float4*)a.src[idx])[off];
  ushort4 o;
  o.x = f2bf(v.x); o.y = f2bf(v.y); o.z = f2bf(v.z); o.w = f2bf(v.w);
  ((ushort4*)a.dst[idx])[off] = o;
}

// =====================================================================
// 256x256 GEMM, read-ahead 4-phase schedule: C[M,N] = A[M,K] @ B[N,K]^T.
// 512 threads = 8 waves (2M x 4N), per-wave 128x64 out, BK=64.
// LDS 128KB double-buffered; T2 XOR swizzle (conflict-free, r2-verified).
// Per phase: [ds_reads for NEXT quadrant][2 G2L][barrier][counted lgkm]
// [setprio 16 MFMA][barrier] -> LDS drain overlaps MFMA (T3+T4+T5).
// Quadrant order M0=A03xB01 M1=A47xB01 M2=A03xB23 M3=A47xB23 gives each
// frag a single read/K-tile and natural register recycling.
// Staging split by read-region so each overwrite is ordered after the
// barrier that confirms that region's reads: A03@ph1, A47@ph2, B1@ph3,
// B2@ph0(next). One counted vmcnt(4) per K-tile (phase 2).
// =====================================================================
#define EPI_PROJ 0
#define EPI_SCALE 1
#define EPI_OUT 2

struct G256 {
  const unsigned short* A;
  const unsigned short* B;
  unsigned short* C;            // bf16 out (EPI_SCALE) or cast to float* (EPI_OUT)
  unsigned short* outQ; unsigned short* outK; unsigned short* outV;
  const float* biasQ; const float* biasK; const float* biasV;
  long long batchA, batchB, batchC;
  int lda, ldb, ldc, K;
  float scale;
};

#define G2L(gp, lp) __builtin_amdgcn_global_load_lds( \
    (const __attribute__((address_space(1))) void*)(gp), \
    (__attribute__((address_space(3))) void*)(lp), 16, 0, 0)

#define MFMA_(d, a, b) d = __builtin_amdgcn_mfma_f32_16x16x32_bf16(a, b, d, 0, 0, 0)
#define SB0() __builtin_amdgcn_sched_barrier(0)

template<int EPI>
__global__ __launch_bounds__(512, 2) void gemm256(G256 p) {
  extern __shared__ char smem[]; // 131072 bytes
  char* smA = smem;
  char* smB = smem + 65536;

  const int tid = threadIdx.x;
  const int lane = tid & 63;
  const int wave = tid >> 6;
  const int wm = wave >> 2;   // 0..1
  const int wn = wave & 3;    // 0..3

  // bijective XCD-aware block swizzle (m204 variant)
  const int gx = gridDim.x, gy = gridDim.y;
  const int nwg = gx * gy * (int)gridDim.z;
  int orig = blockIdx.x + gx * (blockIdx.y + gy * blockIdx.z);
  int qq = nwg >> 3, rr_ = nwg & 7;
  int xcd = orig & 7, sl = orig >> 3;
  int wg = (xcd < rr_ ? xcd * (qq + 1) : rr_ * (qq + 1) + (xcd - rr_) * qq) + sl;
  int bx = wg % gx;
  int t2 = wg / gx;
  int by = t2 % gy;
  int z  = t2 / gy;

  const int m0 = by << 8, n0 = bx << 8;

  const long long lda2 = (long long)p.lda * 2;
  const long long ldb2 = (long long)p.ldb * 2;
  const char* Abase = (const char*)(p.A + (long long)z * p.batchA) + (long long)m0 * lda2;
  const char* Bbase = (const char*)(p.B + (long long)z * p.batchB) + (long long)n0 * ldb2;

  // staging: thread covers LDS linear slot c*8192 + tid*16 (c=0..3);
  // row = c*64 + tid/8 ; source col pre-inverse-swizzled
  const int trow = tid >> 3;
  const int cs = (((tid & 7) ^ (trow & 7)) << 4);
  const char* srcA = Abase + (long long)trow * lda2 + cs;
  const char* srcB = Bbase + (long long)trow * ldb2 + cs;

  const int NT = p.K >> 6;

  // swizzled ds_read offsets
  const int arow = ((wm << 7) + (lane & 15)) << 7;  // A row byte base
  const int brow = ((wn << 6) + (lane & 15)) << 7;  // B row byte base
  const int csw = (lane & 7) << 4;
  const int ck0 = (((lane >> 4) << 4)) ^ csw;
  const int ck1 = ((((lane >> 4) << 4)) | 64) ^ csw;

  f32x4 acc[8][4];
#pragma unroll
  for (int i = 0; i < 8; ++i)
#pragma unroll
    for (int j = 0; j < 4; ++j) acc[i][j] = (f32x4){0.f, 0.f, 0.f, 0.f};

  bf16x8 af[4][2], ag[4][2], bf[2][2], bg[2][2];

  // G2L chunk issuers. Rows per chunk c: [c*64,(c+1)*64).
  // A03 frag region = rows [0,64)u[128,192) = c{0,2}; A47 = c{1,3}.
  auto stA03 = [&](int t) {
    char* d = smA + ((t & 1) << 15) + (tid << 4);
    const char* s = srcA + (long long)t * 128;
    G2L(s, d);
    G2L(s + (lda2 << 7), d + 16384);             // c=2: +128 rows, +16KB
  };
  auto stA47 = [&](int t) {
    char* d = smA + ((t & 1) << 15) + (tid << 4);
    const char* s = srcA + (long long)t * 128;
    G2L(s + (lda2 << 6), d + 8192);              // c=1
    G2L(s + 3 * (lda2 << 6), d + 24576);         // c=3
  };
  auto stB1 = [&](int t) {
    char* d = smB + ((t & 1) << 15) + (tid << 4);
    const char* s = srcB + (long long)t * 128;
    G2L(s, d);                                    // c=0
    G2L(s + (ldb2 << 6), d + 8192);              // c=1
  };
  auto stB2 = [&](int t) {
    char* d = smB + ((t & 1) << 15) + (tid << 4);
    const char* s = srcB + (long long)t * 128;
    G2L(s + 2 * (ldb2 << 6), d + 16384);         // c=2
    G2L(s + 3 * (ldb2 << 6), d + 24576);         // c=3
  };

  // R0 reads: af (A03, 8) + bf (B01, 4) from buffer of tile t
  auto readR0 = [&](int t) {
    const char* ra = smA + ((t & 1) << 15);
    const char* rb = smB + ((t & 1) << 15);
#pragma unroll
    for (int mi = 0; mi < 4; ++mi) {
      af[mi][0] = *(const bf16x8*)(ra + arow + (mi << 11) + ck0);
      af[mi][1] = *(const bf16x8*)(ra + arow + (mi << 11) + ck1);
    }
#pragma unroll
    for (int ni = 0; ni < 2; ++ni) {
      bf[ni][0] = *(const bf16x8*)(rb + brow + (ni << 11) + ck0);
      bf[ni][1] = *(const bf16x8*)(rb + brow + (ni << 11) + ck1);
    }
  };

  // prologue: stage tile0 fully + tile1 (A03,A47,B1); wait tile0; read R0(0)
  stA03(0); stA47(0); stB1(0); stB2(0);
  stA03(1); stA47(1); stB1(1);
  asm volatile("s_waitcnt vmcnt(6)" ::: "memory");
  __builtin_amdgcn_s_barrier();
  SB0();
  readR0(0);

  for (int t = 0; t < NT; ++t) {
    const char* ra = smA + ((t & 1) << 15);
    const char* rb = smB + ((t & 1) << 15);
    const bool pf1 = (t + 1) < NT;
    const bool pf2 = (t + 2) < NT;

    // ---------------- phase 0: read R1(ag); G2L B2(t+1); M0 = af x bf ----
#pragma unroll
    for (int mi = 0; mi < 4; ++mi) {
      ag[mi][0] = *(const bf16x8*)(ra + arow + ((mi + 4) << 11) + ck0);
      ag[mi][1] = *(const bf16x8*)(ra + arow + ((mi + 4) << 11) + ck1);
    }
    if (pf1) stB2(t + 1);
    SB0();
    __builtin_amdgcn_s_barrier();
    asm volatile("s_waitcnt lgkmcnt(8)" ::: "memory");
    SB0();
    __builtin_amdgcn_s_setprio(1);
#pragma unroll
    for (int mi = 0; mi < 4; ++mi)
#pragma unroll
      for (int ni = 0; ni < 2; ++ni) {
        MFMA_(acc[mi][ni], af[mi][0], bf[ni][0]);
        MFMA_(acc[mi][ni], af[mi][1], bf[ni][1]);
      }
    __builtin_amdgcn_s_setprio(0);
    __builtin_amdgcn_s_barrier();

    // ---------------- phase 1: read R2(bg); G2L A03(t+2); M1 = ag x bf ---
#pragma unroll
    for (int ni = 0; ni < 2; ++ni) {
      bg[ni][0] = *(const bf16x8*)(rb + brow + ((ni + 2) << 11) + ck0);
      bg[ni][1] = *(const bf16x8*)(rb + brow + ((ni + 2) << 11) + ck1);
    }
    if (pf2) stA03(t + 2);
    SB0();
    __builtin_amdgcn_s_barrier();
    asm volatile("s_waitcnt lgkmcnt(4)" ::: "memory");
    SB0();
    __builtin_amdgcn_s_setprio(1);
#pragma unroll
    for (int mi = 0; mi < 4; ++mi)
#pragma unroll
      for (int ni = 0; ni < 2; ++ni) {
        MFMA_(acc[mi + 4][ni], ag[mi][0], bf[ni][0]);
        MFMA_(acc[mi + 4][ni], ag[mi][1], bf[ni][1]);
      }
    __builtin_amdgcn_s_setprio(0);
    __builtin_amdgcn_s_barrier();

    // ---------------- phase 2: G2L A47(t+2); M2 = af x bg; vmcnt ---------
    if (pf2) stA47(t + 2);
    SB0();
    __builtin_amdgcn_s_barrier();
    asm volatile("s_waitcnt lgkmcnt(0)" ::: "memory");
    SB0();
    __builtin_amdgcn_s_setprio(1);
#pragma unroll
    for (int mi = 0; mi < 4; ++mi)
#pragma unroll
      for (int ni = 0; ni < 2; ++ni) {
        MFMA_(acc[mi][ni + 2], af[mi][0], bg[ni][0]);
        MFMA_(acc[mi][ni + 2], af[mi][1], bg[ni][1]);
      }
    __builtin_amdgcn_s_setprio(0);
    if (pf1) { asm volatile("s_waitcnt vmcnt(4)" ::: "memory"); }
    __builtin_amdgcn_s_barrier();

    // ---------------- phase 3: read R0(t+1); G2L B1(t+2); M3 = ag x bg ---
    if (pf1) readR0(t + 1);
    if (pf2) stB1(t + 2);
    SB0();
    __builtin_amdgcn_s_barrier();
    SB0();
    __builtin_amdgcn_s_setprio(1);
#pragma unroll
    for (int mi = 0; mi < 4; ++mi)
#pragma unroll
      for (int ni = 0; ni < 2; ++ni) {
        MFMA_(acc[mi + 4][ni + 2], ag[mi][0], bg[ni][0]);
        MFMA_(acc[mi + 4][ni + 2], ag[mi][1], bg[ni][1]);
      }
    __builtin_amdgcn_s_setprio(0);
    __builtin_amdgcn_s_barrier();
  }

  // ---------- epilogue ----------
  const int c0 = lane & 15;
  const int r0 = (lane >> 4) << 2;
  if constexpr (EPI == EPI_SCALE) {
    unsigned short* Cz = p.C + (long long)z * p.batchC;
#pragma unroll
    for (int mi = 0; mi < 8; ++mi) {
      const int grow = m0 + (wm << 7) + (mi << 4) + r0;
#pragma unroll
      for (int ni = 0; ni < 4; ++ni) {
        const int gcol = n0 + (wn << 6) + (ni << 4) + c0;
#pragma unroll
        for (int rr = 0; rr < 4; ++rr)
          Cz[(long long)(grow + rr) * p.ldc + gcol] = f2bf(acc[mi][ni][rr] * p.scale);
      }
    }
  } else if constexpr (EPI == EPI_OUT) {
    float* Cz = (float*)p.C + (long long)z * p.batchC;
#pragma unroll
    for (int mi = 0; mi < 8; ++mi) {
      const int grow = m0 + (wm << 7) + (mi << 4) + r0;
#pragma unroll
      for (int ni = 0; ni < 4; ++ni) {
        const int gcol = n0 + (wn << 6) + (ni << 4) + c0;
#pragma unroll
        for (int rr = 0; rr < 4; ++rr)
          Cz[(long long)(grow + rr) * p.ldc + gcol] = acc[mi][ni][rr] * p.scale;
      }
    }
  } else { // EPI_PROJ
    if (z < 2) {
      unsigned short* O = (z == 0) ? p.outQ : p.outK;
      const float* bias = (z == 0) ? p.biasQ : p.biasK;
#pragma unroll
      for (int mi = 0; mi < 8; ++mi) {
        const int grow = m0 + (wm << 7) + (mi << 4) + r0;
#pragma unroll
        for (int ni = 0; ni < 4; ++ni) {
          const int gcol = n0 + (wn << 6) + (ni << 4) + c0;
          const float bb = bias[gcol];
#pragma unroll
          for (int rr = 0; rr < 4; ++rr)
            O[(long long)(grow + rr) * 1024 + gcol] = f2bf(acc[mi][ni][rr] + bb);
        }
      }
    } else { // v projection, transposed out: vT[b][d][s]
#pragma unroll
      for (int mi = 0; mi < 8; ++mi) {
        const int grow = m0 + (wm << 7) + (mi << 4) + r0;
        const int bb = grow >> 11, s = grow & 2047;
#pragma unroll
        for (int ni = 0; ni < 4; ++ni) {
          const int d = n0 + (wn << 6) + (ni << 4) + c0;
          const float ba = p.biasV[d];
          ushort4 pk;
          pk.x = f2bf(acc[mi][ni][0] + ba);
          pk.y = f2bf(acc[mi][ni][1] + ba);
          pk.z = f2bf(acc[mi][ni][2] + ba);
          pk.w = f2bf(acc[mi][ni][3] + ba);
          *(ushort4*)(p.outV + ((long long)bb << 21) + (long long)d * 2048 + s) = pk;
        }
      }
    }
  }
}

// ---------- row softmax over S[4][2048][2048] (bf16, in place) ----------
__global__ __launch_bounds__(256) void softmax_rows(unsigned short* __restrict__ S) {
  const size_t row = blockIdx.x;
  unsigned short* pp = S + row * 2048;
  const int t = threadIdx.x, lane = t & 63, wave = t >> 6;
  u16x8 h = ((const u16x8*)pp)[t];
  float x[8];
#pragma unroll
  for (int j = 0; j < 8; ++j) x[j] = bf2f(h[j]);
  float m = x[0];
#pragma unroll
  for (int j = 1; j < 8; ++j) m = fmaxf(m, x[j]);
#pragma unroll
  for (int off = 32; off >= 1; off >>= 1) m = fmaxf(m, __shfl_xor(m, off, 64));
  __shared__ float rmax[4], rsum[4];
  if (lane == 0) rmax[wave] = m;
  __syncthreads();
  m = fmaxf(fmaxf(rmax[0], rmax[1]), fmaxf(rmax[2], rmax[3]));
  float e[8], sum = 0.f;
#pragma unroll
  for (int j = 0; j < 8; ++j) { e[j] = __expf(x[j] - m); sum += e[j]; }
#pragma unroll
  for (int off = 32; off >= 1; off >>= 1) sum += __shfl_xor(sum, off, 64);
  if (lane == 0) rsum[wave] = sum;
  __syncthreads();
  sum = rsum[0] + rsum[1] + rsum[2] + rsum[3];
  const float inv = 1.f / sum;
  u16x8 o;
#pragma unroll
  for (int j = 0; j < 8; ++j) o[j] = f2bf(e[j] * inv);
  ((u16x8*)pp)[t] = o;
}

// ---------- launch ----------
extern "C" void kernel_launch(void* const* d_in, const int* in_sizes, int n_in,
                              void* d_out, int out_size, void* d_ws, size_t ws_size,
                              hipStream_t stream) {
  const float* q  = (const float*)d_in[0];
  const float* k  = (const float*)d_in[1];
  const float* v  = (const float*)d_in[2];
  const float* Wq = (const float*)d_in[3];
  const float* bq = (const float*)d_in[4];
  const float* Wk = (const float*)d_in[5];
  const float* bk = (const float*)d_in[6];
  const float* Wv = (const float*)d_in[7];
  const float* bv = (const float*)d_in[8];

  // workspace (u16 elems): Xb 48MB (S 32MB overlays it later), Wb 6MB,
  // qb 16MB, kb 16MB, vT 16MB -> 102MB total
  unsigned short* Xb = (unsigned short*)d_ws;
  unsigned short* Wb = Xb + 25165824;
  unsigned short* qb = Wb + 3145728;
  unsigned short* kb = qb + 8388608;
  unsigned short* vT = kb + 8388608;
  unsigned short* S  = Xb;

  (void)hipFuncSetAttribute((const void*)gemm256<EPI_PROJ>,
      hipFuncAttributeMaxDynamicSharedMemorySize, 131072);
  (void)hipFuncSetAttribute((const void*)gemm256<EPI_SCALE>,
      hipFuncAttributeMaxDynamicSharedMemorySize, 131072);
  (void)hipFuncSetAttribute((const void*)gemm256<EPI_OUT>,
      hipFuncAttributeMaxDynamicSharedMemorySize, 131072);

  CvtArgs ca;
  ca.src[0] = q;  ca.src[1] = k;  ca.src[2] = v;
  ca.src[3] = Wq; ca.src[4] = Wk; ca.src[5] = Wv;
  ca.dst[0] = Xb;            ca.dst[1] = Xb + 8388608; ca.dst[2] = Xb + 16777216;
  ca.dst[3] = Wb;            ca.dst[4] = Wb + 1048576; ca.dst[5] = Wb + 2097152;
  cvt6<<<27648, 256, 0, stream>>>(ca);

  // fused q/k/v projections: per z, M=8192, N=1024, K=1024
  G256 gp{};
  gp.A = Xb;  gp.batchA = 8388608; gp.lda = 1024;
  gp.B = Wb;  gp.batchB = 1048576; gp.ldb = 1024;
  gp.outQ = qb; gp.outK = kb; gp.outV = vT;
  gp.biasQ = bq; gp.biasK = bk; gp.biasV = bv;
  gp.K = 1024; gp.scale = 1.f;
  gemm256<EPI_PROJ><<<dim3(4, 32, 3), 512, 131072, stream>>>(gp);

  // scores = q @ k^T * scale : per batch M=2048, N=2048, K=1024
  G256 gs{};
  gs.A = qb; gs.batchA = 2097152; gs.lda = 1024;
  gs.B = kb; gs.batchB = 2097152; gs.ldb = 1024;
  gs.C = S;  gs.batchC = 4194304; gs.ldc = 2048;
  gs.K = 1024; gs.scale = 0.03125f;
  gemm256<EPI_SCALE><<<dim3(8, 8, 4), 512, 131072, stream>>>(gs);

  softmax_rows<<<8192, 256, 0, stream>>>(S);

  // out = P @ V : M=2048, N=1024, K=2048 per batch
  G256 gv{};
  gv.A = S;  gv.batchA = 4194304; gv.lda = 2048;
  gv.B = vT; gv.batchB = 2097152; gv.ldb = 2048;
  gv.C = (unsigned short*)d_out; gv.batchC = 2097152; gv.ldc = 1024;
  gv.K = 2048; gv.scale = 1.f;
  gemm256<EPI_OUT><<<dim3(4, 8, 4), 512, 131072, stream>>>(gv);
}

// Round 4
// 178.711 us; speedup vs baseline: 1.1703x; 1.1703x over previous
//
#include <hip/hip_runtime.h>

// ---------- types ----------
typedef __bf16 bf16x8 __attribute__((ext_vector_type(8)));
typedef float f32x4 __attribute__((ext_vector_type(4)));
typedef unsigned short u16x8 __attribute__((ext_vector_type(8)));

__device__ inline unsigned short f2bf(float f) {
  union { float f; unsigned u; } a; a.f = f;
  return (unsigned short)((a.u + 0x7fffu + ((a.u >> 16) & 1u)) >> 16); // RNE
}
__device__ inline float bf2f(unsigned short h) {
  union { unsigned u; float f; } a; a.u = ((unsigned)h) << 16;
  return a.f;
}

// ---------- fp32 -> bf16 conversion (query,key,value,Wq,Wk,Wv) ----------
struct CvtArgs {
  const float* src[6];
  unsigned short* dst[6];
};

__global__ __launch_bounds__(256) void cvt6(CvtArgs a) {
  long long i = (long long)blockIdx.x * 256 + threadIdx.x; // one float4 each
  int idx; long long off;
  if (i < 6291456LL) { idx = (int)(i >> 21); off = i & ((1LL << 21) - 1); }
  else { long long j = i - 6291456LL; idx = 3 + (int)(j >> 18); off = j & ((1LL << 18) - 1); }
  float4 v = ((const float4*)a.src[idx])[off];
  ushort4 o;
  o.x = f2bf(v.x); o.y = f2bf(v.y); o.z = f2bf(v.z); o.w = f2bf(v.w);
  ((ushort4*)a.dst[idx])[off] = o;
}

// =====================================================================
// bf16 GEMM C[M,N] = A[M,K] @ B[N,K]^T, one-barrier-per-K-tile schedule.
// 512 thr = 8 waves on a BM x BN tile, per-wave WMW x WNW, BK=64.
// Per-wave rolling pipeline: frag reads issued one quadrant ahead,
// per-wave counted lgkm waits (waves de-phase; LDS drain overlaps other
// waves' MFMA). Staging: global_load_lds, issued once per tile right
// after the single barrier, one-full-tile-deep window. T2 XOR swizzle.
// =====================================================================
#define EPI_PROJ 0
#define EPI_SCALE 1
#define EPI_OUT 2

struct GP {
  const unsigned short* A;
  const unsigned short* B;
  unsigned short* C;            // bf16 out (EPI_SCALE) or float* (EPI_OUT)
  unsigned short* outQ; unsigned short* outK; unsigned short* outV;
  const float* biasQ; const float* biasK; const float* biasV;
  long long batchA, batchB, batchC;
  int lda, ldb, ldc, K;
  float scale;
};

#define G2L(gp, lp) __builtin_amdgcn_global_load_lds( \
    (const __attribute__((address_space(1))) void*)(gp), \
    (__attribute__((address_space(3))) void*)(lp), 16, 0, 0)

#define MFMA_(d, a, b) d = __builtin_amdgcn_mfma_f32_16x16x32_bf16(a, b, d, 0, 0, 0)
#define SB0() __builtin_amdgcn_sched_barrier(0)
#define LGKM(n) do { asm volatile("s_waitcnt lgkmcnt(" #n ")" ::: "memory"); SB0(); } while (0)
#define VMC(n) do { asm volatile("s_waitcnt vmcnt(" #n ")" ::: "memory"); SB0(); } while (0)

template<int BM, int BN, int WMW, int WNW, int EPI>
__global__ __launch_bounds__(512, 2) void gemm2(GP p) {
  constexpr int WAVES_N = BN / WNW;
  constexpr int AMF = WMW / 16;           // A frags (m) per k-slot per wave
  constexpr int BNF = WNW / 16;           // B frags (n) per k-slot per wave
  constexpr int AH = AMF / 2, BH = BNF / 2;
  constexpr int AF_N = AH * 2;            // reads per A-half set (8 or 4)
  constexpr int NBA = BM / 64, NBB = BN / 64; // G2L per thread per tile
  static_assert((BM / WMW) * WAVES_N == 8, "8 waves");
  static_assert(BNF == 4, "BF_N==4 assumed by lgkm immediates");

  extern __shared__ char smem[];          // 2*(BM+BN)*128 bytes
  char* smA = smem;                       // buf b at b*BM*128
  char* smB = smem + 2 * BM * 128;        // buf b at b*BN*128

  const int tid = threadIdx.x;
  const int lane = tid & 63;
  const int wid = tid >> 6;
  const int wm = wid / WAVES_N, wn = wid % WAVES_N;

  // bijective XCD-aware block swizzle (m204)
  const int gx = gridDim.x, gy = gridDim.y;
  const int nwg = gx * gy * (int)gridDim.z;
  int orig = blockIdx.x + gx * (blockIdx.y + gy * blockIdx.z);
  int qq = nwg >> 3, rr_ = nwg & 7;
  int xcd = orig & 7, sl = orig >> 3;
  int wg = (xcd < rr_ ? xcd * (qq + 1) : rr_ * (qq + 1) + (xcd - rr_) * qq) + sl;
  int bx = wg % gx;
  int t2 = wg / gx;
  int by = t2 % gy;
  int z  = t2 / gy;

  const int m0 = by * BM, n0 = bx * BN;

  const long long lda2 = (long long)p.lda * 2;
  const long long ldb2 = (long long)p.ldb * 2;
  const char* Abase = (const char*)(p.A + (long long)z * p.batchA) + (long long)m0 * lda2;
  const char* Bbase = (const char*)(p.B + (long long)z * p.batchB) + (long long)n0 * ldb2;

  // staging source: thread covers LDS linear slot c*8192 + tid*16;
  // row = c*64 + tid/8, source col pre-inverse-swizzled
  const int trow = tid >> 3;
  const int cs = (((tid & 7) ^ (trow & 7)) << 4);
  const char* srcA = Abase + (long long)trow * lda2 + cs;
  const char* srcB = Bbase + (long long)trow * ldb2 + cs;

  const int NT = p.K >> 6;

  // swizzled ds_read offsets
  const int aRowB = ((wm * WMW + (lane & 15)) << 7);
  const int bRowB = ((wn * WNW + (lane & 15)) << 7);
  const int csw = (lane & 7) << 4;
  const int ck0 = (((lane >> 4) << 4)) ^ csw;
  const int ck1 = ((((lane >> 4) << 4)) | 64) ^ csw;

  f32x4 acc[AMF][BNF];
#pragma unroll
  for (int i = 0; i < AMF; ++i)
#pragma unroll
    for (int j = 0; j < BNF; ++j) acc[i][j] = (f32x4){0.f, 0.f, 0.f, 0.f};

  bf16x8 aLo[AH][2], aHi[AH][2], bLo[BH][2], bHi[BH][2];

  auto stage = [&](int t) {
    char* dA = smA + (t & 1) * (BM * 128) + (tid << 4);
    char* dB = smB + (t & 1) * (BN * 128) + (tid << 4);
    const char* sA = srcA + (long long)t * 128;
    const char* sB = srcB + (long long)t * 128;
#pragma unroll
    for (int c = 0; c < NBA; ++c) G2L(sA + (long long)c * (lda2 << 6), dA + c * 8192);
#pragma unroll
    for (int c = 0; c < NBB; ++c) G2L(sB + (long long)c * (ldb2 << 6), dB + c * 8192);
  };
  auto readAh = [&](int t, int half, bf16x8 (&dst)[AH][2]) {
    const char* ra = smA + (t & 1) * (BM * 128) + aRowB + half * (AH * 2048);
#pragma unroll
    for (int mi = 0; mi < AH; ++mi) {
      dst[mi][0] = *(const bf16x8*)(ra + mi * 2048 + ck0);
      dst[mi][1] = *(const bf16x8*)(ra + mi * 2048 + ck1);
    }
  };
  auto readBh = [&](int t, int half, bf16x8 (&dst)[BH][2]) {
    const char* rb = smB + (t & 1) * (BN * 128) + bRowB + half * (BH * 2048);
#pragma unroll
    for (int ni = 0; ni < BH; ++ni) {
      dst[ni][0] = *(const bf16x8*)(rb + ni * 2048 + ck0);
      dst[ni][1] = *(const bf16x8*)(rb + ni * 2048 + ck1);
    }
  };
  auto quad = [&](int qa, int qb, bf16x8 (&A)[AH][2], bf16x8 (&B)[BH][2]) {
    __builtin_amdgcn_s_setprio(1);
#pragma unroll
    for (int mi = 0; mi < AH; ++mi)
#pragma unroll
      for (int ni = 0; ni < BH; ++ni) {
        MFMA_(acc[qa * AH + mi][qb * BH + ni], A[mi][0], B[ni][0]);
        MFMA_(acc[qa * AH + mi][qb * BH + ni], A[mi][1], B[ni][1]);
      }
    __builtin_amdgcn_s_setprio(0);
  };

  // ---- prologue: stage tiles 0,1; confirm 0; pre-read af/bf(0) ----
  stage(0); stage(1);
  if constexpr (NBA + NBB == 8) VMC(8); else VMC(6);
  __builtin_amdgcn_s_barrier();
  readAh(0, 0, aLo); readBh(0, 0, bLo);
  SB0();

  for (int t = 0; t < NT; ++t) {
    readAh(t, 1, aHi);                 // ag
    SB0();
    if constexpr (AF_N == 8) LGKM(8); else LGKM(4);  // af,bf ready
    quad(0, 0, aLo, bLo);
    readBh(t, 1, bHi);                 // bg
    SB0();
    LGKM(4);                           // ag ready
    quad(1, 0, aHi, bLo);
    LGKM(0);                           // bg ready
    quad(0, 1, aLo, bHi);
    quad(1, 1, aHi, bHi);
    VMC(0);                            // stage(t+1) (1 tile old) landed
    __builtin_amdgcn_s_barrier();      // all waves done reading tile t
    if (t + 2 < NT) stage(t + 2);      // into buffer (t&1), now free
    if (t + 1 < NT) { readAh(t + 1, 0, aLo); readBh(t + 1, 0, bLo); }
    SB0();
  }

  // ---------- epilogue ----------
  const int c0 = lane & 15;
  const int r0 = (lane >> 4) << 2;
  if constexpr (EPI == EPI_SCALE) {
    unsigned short* Cz = p.C + (long long)z * p.batchC;
#pragma unroll
    for (int mi = 0; mi < AMF; ++mi) {
      const int grow = m0 + wm * WMW + (mi << 4) + r0;
#pragma unroll
      for (int ni = 0; ni < BNF; ++ni) {
        const int gcol = n0 + wn * WNW + (ni << 4) + c0;
#pragma unroll
        for (int rr = 0; rr < 4; ++rr)
          Cz[(long long)(grow + rr) * p.ldc + gcol] = f2bf(acc[mi][ni][rr] * p.scale);
      }
    }
  } else if constexpr (EPI == EPI_OUT) {
    float* Cz = (float*)p.C + (long long)z * p.batchC;
#pragma unroll
    for (int mi = 0; mi < AMF; ++mi) {
      const int grow = m0 + wm * WMW + (mi << 4) + r0;
#pragma unroll
      for (int ni = 0; ni < BNF; ++ni) {
        const int gcol = n0 + wn * WNW + (ni << 4) + c0;
#pragma unroll
        for (int rr = 0; rr < 4; ++rr)
          Cz[(long long)(grow + rr) * p.ldc + gcol] = acc[mi][ni][rr] * p.scale;
      }
    }
  } else { // EPI_PROJ
    if (z < 2) {
      unsigned short* O = (z == 0) ? p.outQ : p.outK;
      const float* bias = (z == 0) ? p.biasQ : p.biasK;
#pragma unroll
      for (int mi = 0; mi < AMF; ++mi) {
        const int grow = m0 + wm * WMW + (mi << 4) + r0;
#pragma unroll
        for (int ni = 0; ni < BNF; ++ni) {
          const int gcol = n0 + wn * WNW + (ni << 4) + c0;
          const float bb = bias[gcol];
#pragma unroll
          for (int rr = 0; rr < 4; ++rr)
            O[(long long)(grow + rr) * 1024 + gcol] = f2bf(acc[mi][ni][rr] + bb);
        }
      }
    } else { // v projection, transposed out: vT[b][d][s]
#pragma unroll
      for (int mi = 0; mi < AMF; ++mi) {
        const int grow = m0 + wm * WMW + (mi << 4) + r0;
        const int bb = grow >> 11, s = grow & 2047;
#pragma unroll
        for (int ni = 0; ni < BNF; ++ni) {
          const int d = n0 + wn * WNW + (ni << 4) + c0;
          const float ba = p.biasV[d];
          ushort4 pk;
          pk.x = f2bf(acc[mi][ni][0] + ba);
          pk.y = f2bf(acc[mi][ni][1] + ba);
          pk.z = f2bf(acc[mi][ni][2] + ba);
          pk.w = f2bf(acc[mi][ni][3] + ba);
          *(ushort4*)(p.outV + ((long long)bb << 21) + (long long)d * 2048 + s) = pk;
        }
      }
    }
  }
}

// ---------- row softmax over S[4][2048][2048] (bf16, in place) ----------
__global__ __launch_bounds__(256) void softmax_rows(unsigned short* __restrict__ S) {
  const size_t row = blockIdx.x;
  unsigned short* pp = S + row * 2048;
  const int t = threadIdx.x, lane = t & 63, wave = t >> 6;
  u16x8 h = ((const u16x8*)pp)[t];
  float x[8];
#pragma unroll
  for (int j = 0; j < 8; ++j) x[j] = bf2f(h[j]);
  float m = x[0];
#pragma unroll
  for (int j = 1; j < 8; ++j) m = fmaxf(m, x[j]);
#pragma unroll
  for (int off = 32; off >= 1; off >>= 1) m = fmaxf(m, __shfl_xor(m, off, 64));
  __shared__ float rmax[4], rsum[4];
  if (lane == 0) rmax[wave] = m;
  __syncthreads();
  m = fmaxf(fmaxf(rmax[0], rmax[1]), fmaxf(rmax[2], rmax[3]));
  float e[8], sum = 0.f;
#pragma unroll
  for (int j = 0; j < 8; ++j) { e[j] = __expf(x[j] - m); sum += e[j]; }
#pragma unroll
  for (int off = 32; off >= 1; off >>= 1) sum += __shfl_xor(sum, off, 64);
  if (lane == 0) rsum[wave] = sum;
  __syncthreads();
  sum = rsum[0] + rsum[1] + rsum[2] + rsum[3];
  const float inv = 1.f / sum;
  u16x8 o;
#pragma unroll
  for (int j = 0; j < 8; ++j) o[j] = f2bf(e[j] * inv);
  ((u16x8*)pp)[t] = o;
}

// ---------- launch ----------
extern "C" void kernel_launch(void* const* d_in, const int* in_sizes, int n_in,
                              void* d_out, int out_size, void* d_ws, size_t ws_size,
                              hipStream_t stream) {
  const float* q  = (const float*)d_in[0];
  const float* k  = (const float*)d_in[1];
  const float* v  = (const float*)d_in[2];
  const float* Wq = (const float*)d_in[3];
  const float* bq = (const float*)d_in[4];
  const float* Wk = (const float*)d_in[5];
  const float* bk = (const float*)d_in[6];
  const float* Wv = (const float*)d_in[7];
  const float* bv = (const float*)d_in[8];

  // workspace (u16 elems): Xb 48MB (S 32MB overlays it later), Wb 6MB,
  // qb 16MB, kb 16MB, vT 16MB -> 102MB total
  unsigned short* Xb = (unsigned short*)d_ws;
  unsigned short* Wb = Xb + 25165824;
  unsigned short* qb = Wb + 3145728;
  unsigned short* kb = qb + 8388608;
  unsigned short* vT = kb + 8388608;
  unsigned short* S  = Xb;

  (void)hipFuncSetAttribute((const void*)gemm2<256,128,64,64,EPI_PROJ>,
      hipFuncAttributeMaxDynamicSharedMemorySize, 98304);
  (void)hipFuncSetAttribute((const void*)gemm2<256,256,128,64,EPI_SCALE>,
      hipFuncAttributeMaxDynamicSharedMemorySize, 131072);
  (void)hipFuncSetAttribute((const void*)gemm2<256,128,64,64,EPI_OUT>,
      hipFuncAttributeMaxDynamicSharedMemorySize, 98304);

  CvtArgs ca;
  ca.src[0] = q;  ca.src[1] = k;  ca.src[2] = v;
  ca.src[3] = Wq; ca.src[4] = Wk; ca.src[5] = Wv;
  ca.dst[0] = Xb;            ca.dst[1] = Xb + 8388608; ca.dst[2] = Xb + 16777216;
  ca.dst[3] = Wb;            ca.dst[4] = Wb + 1048576; ca.dst[5] = Wb + 2097152;
  cvt6<<<27648, 256, 0, stream>>>(ca);

  // fused q/k/v projections: per z, M=8192, N=1024, K=1024 (768 WGs)
  GP gp{};
  gp.A = Xb;  gp.batchA = 8388608; gp.lda = 1024;
  gp.B = Wb;  gp.batchB = 1048576; gp.ldb = 1024;
  gp.outQ = qb; gp.outK = kb; gp.outV = vT;
  gp.biasQ = bq; gp.biasK = bk; gp.biasV = bv;
  gp.K = 1024; gp.scale = 1.f;
  gemm2<256,128,64,64,EPI_PROJ><<<dim3(8, 32, 3), 512, 98304, stream>>>(gp);

  // scores = q @ k^T * scale : per batch M=2048, N=2048, K=1024 (256 WGs)
  GP gs{};
  gs.A = qb; gs.batchA = 2097152; gs.lda = 1024;
  gs.B = kb; gs.batchB = 2097152; gs.ldb = 1024;
  gs.C = S;  gs.batchC = 4194304; gs.ldc = 2048;
  gs.K = 1024; gs.scale = 0.03125f;
  gemm2<256,256,128,64,EPI_SCALE><<<dim3(8, 8, 4), 512, 131072, stream>>>(gs);

  softmax_rows<<<8192, 256, 0, stream>>>(S);

  // out = P @ V : M=2048, N=1024, K=2048 per batch (256 WGs)
  GP gv{};
  gv.A = S;  gv.batchA = 4194304; gv.lda = 2048;
  gv.B = vT; gv.batchB = 2097152; gv.ldb = 2048;
  gv.C = (unsigned short*)d_out; gv.batchC = 2097152; gv.ldc = 1024;
  gv.K = 2048; gv.scale = 1.f;
  gemm2<256,128,64,64,EPI_OUT><<<dim3(8, 8, 4), 512, 98304, stream>>>(gv);
}